// Round 1
// baseline (108.590 us; speedup 1.0000x reference)
//
#include <hip/hip_runtime.h>

// out[row][k] = x[row][k] * Lambda[k] + sum_l B[k][l] * y[row][l]
// rows = b*c*h*w*n = 1,048,576 ; L = 32.
// 8 lanes per row; lane owns quad q = lane&7 -> outputs k = 4q..4q+3.
// B rows for those outputs (128 floats) live in registers, loaded once.
// y quads exchanged within the 8-lane group via __shfl width=8.

__global__ __launch_bounds__(256) void ax_bu_kernel(
    const float* __restrict__ x,
    const float* __restrict__ y,
    const float* __restrict__ Lam,
    const float* __restrict__ B,
    float* __restrict__ out,
    int n4)   // total float4 count = rows * 8
{
    const int q = threadIdx.x & 7;
    const float4 lam = reinterpret_cast<const float4*>(Lam)[q];

    // B[k][l], k = q*4+m, as 8 float4 per output row -> 32 float4 regs
    float4 Bv[4][8];
#pragma unroll
    for (int m = 0; m < 4; ++m)
#pragma unroll
        for (int g = 0; g < 8; ++g)
            Bv[m][g] = reinterpret_cast<const float4*>(B)[(q * 4 + m) * 8 + g];

    const float4* __restrict__ x4 = reinterpret_cast<const float4*>(x);
    const float4* __restrict__ y4 = reinterpret_cast<const float4*>(y);
    float4* __restrict__ o4 = reinterpret_cast<float4*>(out);

    const int stride = gridDim.x * blockDim.x;
    int t = blockIdx.x * blockDim.x + threadIdx.x;
    if (t >= n4) return;

    float4 xv = x4[t];
    float4 yv = y4[t];

    while (true) {
        const int tn = t + stride;
        const bool more = (tn < n4);
        float4 xn, yn;
        if (more) { xn = x4[tn]; yn = y4[tn]; }   // prefetch next tile

        float acc0 = xv.x * lam.x;
        float acc1 = xv.y * lam.y;
        float acc2 = xv.z * lam.z;
        float acc3 = xv.w * lam.w;

#pragma unroll
        for (int g = 0; g < 8; ++g) {
            const float b0 = __shfl(yv.x, g, 8);
            const float b1 = __shfl(yv.y, g, 8);
            const float b2 = __shfl(yv.z, g, 8);
            const float b3 = __shfl(yv.w, g, 8);

            acc0 = fmaf(Bv[0][g].x, b0, acc0);
            acc0 = fmaf(Bv[0][g].y, b1, acc0);
            acc0 = fmaf(Bv[0][g].z, b2, acc0);
            acc0 = fmaf(Bv[0][g].w, b3, acc0);

            acc1 = fmaf(Bv[1][g].x, b0, acc1);
            acc1 = fmaf(Bv[1][g].y, b1, acc1);
            acc1 = fmaf(Bv[1][g].z, b2, acc1);
            acc1 = fmaf(Bv[1][g].w, b3, acc1);

            acc2 = fmaf(Bv[2][g].x, b0, acc2);
            acc2 = fmaf(Bv[2][g].y, b1, acc2);
            acc2 = fmaf(Bv[2][g].z, b2, acc2);
            acc2 = fmaf(Bv[2][g].w, b3, acc2);

            acc3 = fmaf(Bv[3][g].x, b0, acc3);
            acc3 = fmaf(Bv[3][g].y, b1, acc3);
            acc3 = fmaf(Bv[3][g].z, b2, acc3);
            acc3 = fmaf(Bv[3][g].w, b3, acc3);
        }

        o4[t] = make_float4(acc0, acc1, acc2, acc3);

        if (!more) break;
        xv = xn; yv = yn; t = tn;
    }
}

extern "C" void kernel_launch(void* const* d_in, const int* in_sizes, int n_in,
                              void* d_out, int out_size, void* d_ws, size_t ws_size,
                              hipStream_t stream) {
    const float* x   = (const float*)d_in[0];
    const float* y   = (const float*)d_in[1];
    const float* Lam = (const float*)d_in[2];
    const float* B   = (const float*)d_in[3];
    float* out = (float*)d_out;

    const int n4 = in_sizes[0] / 4;          // 8,388,608 float4 elements
    const int block = 256;
    int grid = 2048;                          // 256 CU * 8 blocks; 16 iters/thread
    if (grid * block > n4) grid = (n4 + block - 1) / block;

    ax_bu_kernel<<<grid, block, 0, stream>>>(x, y, Lam, B, out, n4);
}